// Round 4
// baseline (163.560 us; speedup 1.0000x reference)
//
#include <hip/hip_runtime.h>
#include <stdint.h>

typedef __attribute__((ext_vector_type(8))) short short8;
typedef __attribute__((ext_vector_type(8))) __bf16 bf16x8;
typedef __attribute__((ext_vector_type(2))) __bf16 bf16x2;
typedef __attribute__((ext_vector_type(4))) float f32x4;
typedef __attribute__((ext_vector_type(2))) unsigned int uint2_t;
typedef __attribute__((ext_vector_type(2))) float float2_t;

#define LOG2E 1.44269504f

__device__ __forceinline__ unsigned short f2bf(float f) {
  unsigned int u = __builtin_bit_cast(unsigned int, f);
  u += 0x7fffu + ((u >> 16) & 1u);
  return (unsigned short)(u >> 16);
}

// packed f32x2 -> bf16x2 (compiler emits v_cvt_pk_bf16_f32 on gfx950)
__device__ __forceinline__ unsigned int pk2(float a, float b) {
  bf16x2 t;
  t[0] = (__bf16)a;
  t[1] = (__bf16)b;
  return __builtin_bit_cast(unsigned int, t);
}

__device__ __forceinline__ f32x4 mfma16(short8 a, short8 b, f32x4 c) {
  return __builtin_amdgcn_mfma_f32_16x16x32_bf16(
      __builtin_bit_cast(bf16x8, a), __builtin_bit_cast(bf16x8, b), c, 0, 0, 0);
}

__device__ __forceinline__ short8 ld8(const unsigned short* p) {
  return *reinterpret_cast<const short8*>(p);
}

// ---------------- prep: weight cvt (q-scale folded) + scaled wind/elev ----------------
__global__ __launch_bounds__(256) void k_prep(const float* __restrict__ wqkv,
                                              const float* __restrict__ wproj,
                                              const float* __restrict__ u,
                                              const float* __restrict__ v,
                                              const float* __restrict__ elev,
                                              const float* __restrict__ alphap,
                                              unsigned short* __restrict__ wqkv_bf,
                                              unsigned short* __restrict__ wproj_bf,
                                              float* __restrict__ esc,
                                              float* __restrict__ wsc) {
  int gx = blockIdx.x, t = threadIdx.x;
  if (gx < 768) {
    int i = gx * 256 + t;
    // rows [0,256) are q-rows: fold hd^-0.5 * log2e
    float s = (i < 256 * 256) ? (0.17677669529663687f * LOG2E) : 1.0f;
    wqkv_bf[i] = f2bf(wqkv[i] * s);
  } else if (gx < 1024) {
    int i = (gx - 768) * 256 + t;
    wproj_bf[i] = f2bf(wproj[i]);
  } else {
    int i = (gx - 1024) * 256 + t;  // [0, 8192)
    int b = i >> 10, n = i & 1023;
    int ph = n >> 5, pw = n & 31;
    const float* ub = u + b * 4096;
    const float* vb = v + b * 4096;
    float s = 0.f;
#pragma unroll
    for (int dy = 0; dy < 2; ++dy)
#pragma unroll
      for (int dx = 0; dx < 2; ++dx) {
        int idx = (2 * ph + dy) * 64 + (2 * pw + dx);
        float uu = ub[idx], vv = vb[idx];
        s += sqrtf(uu * uu + vv * vv + 1e-8f);
      }
    // wsc = ws * 0.5 * log2e ; esc = elev * alpha * 1e-3 * log2e
    wsc[i] = s * (0.25f * 0.5f * LOG2E);
    esc[i] = elev[i] * (alphap[0] * 1e-3f * LOG2E);
  }
}

// ---------------- QKV GEMM (LDS-staged A, 2 n-tiles/block, v written transposed) ----
__global__ __launch_bounds__(256, 4) void k_qkv(const float* __restrict__ x,
                                                const unsigned short* __restrict__ wq_bf,
                                                unsigned short* __restrict__ qb,
                                                unsigned short* __restrict__ kb,
                                                unsigned short* __restrict__ vT) {
  __shared__ unsigned short xs[64][264];
  const int tid = threadIdx.x;
  const int w = tid >> 6, lane = tid & 63;
  const int c = lane & 15, g = lane >> 4;
  const int m0 = blockIdx.y * 64;
  // cooperative coalesced load + convert
#pragma unroll
  for (int i = 0; i < 16; ++i) {
    int idx = i * 1024 + tid * 4;
    int row = idx >> 8, col = idx & 255;
    f32x4 vv = *reinterpret_cast<const f32x4*>(x + (size_t)(m0 + row) * 256 + col);
    uint2_t hh = {pk2(vv[0], vv[1]), pk2(vv[2], vv[3])};
    *reinterpret_cast<uint2_t*>(&xs[row][col]) = hh;
  }
  __syncthreads();
  for (int nt = 0; nt < 2; ++nt) {
    const int n0 = blockIdx.x * 384 + nt * 192;
    f32x4 acc[12] = {};
#pragma unroll
    for (int k0 = 0; k0 < 256; k0 += 32) {
      short8 af = ld8(&xs[w * 16 + c][k0 + g * 8]);
#pragma unroll
      for (int nb = 0; nb < 12; ++nb) {
        short8 bf = ld8(wq_bf + (size_t)(n0 + nb * 16 + c) * 256 + k0 + g * 8);
        acc[nb] = mfma16(af, bf, acc[nb]);
      }
    }
#pragma unroll
    for (int nb = 0; nb < 12; ++nb) {
      int col = n0 + nb * 16 + c;  // [0,768)
      int s = col >> 8, rem = col & 255;
      int h = rem >> 5, d = rem & 31;
      int nrow0 = m0 + w * 16 + g * 4;  // 4 consecutive rows
      int b = nrow0 >> 10, nn = nrow0 & 1023;
      size_t bh = (size_t)(b * 8 + h);
      if (s == 2) {
        uint2_t pk = {pk2(acc[nb][0], acc[nb][1]), pk2(acc[nb][2], acc[nb][3])};
        *reinterpret_cast<uint2_t*>(vT + (bh * 32 + d) * 1024 + nn) = pk;
      } else {
        unsigned short* dst = (s == 0) ? qb : kb;
#pragma unroll
        for (int r = 0; r < 4; ++r) {
          bf16x2 one;
          one[0] = (__bf16)acc[nb][r];
          dst[(bh * 1024 + nn + r) * 32 + d] = __builtin_bit_cast(unsigned short, one[0]);
        }
      }
    }
  }
}

// ---------------- fused attention: swapped-QK^T, kv-split, f32 bias as MFMA-C ----
// grid: (32 qtiles, 8 b, 4 = hg + 2*sp); block 256 = 4 waves; wave = head hg*4+w
__global__ __launch_bounds__(256, 4) void k_attn(const unsigned short* __restrict__ qb,
                                                 const unsigned short* __restrict__ kb,
                                                 const unsigned short* __restrict__ vT,
                                                 const float* __restrict__ esc,
                                                 const float* __restrict__ wsc,
                                                 const float* __restrict__ betap,
                                                 float* __restrict__ o_part,
                                                 float* __restrict__ ml_part) {
  __shared__ float bias_lds[32][72];
  __shared__ unsigned short p_lds[4][32][72];
  const int tid = threadIdx.x;
  const int w = tid >> 6, lane = tid & 63;
  const int c = lane & 15, g = lane >> 4;
  const int q0 = blockIdx.x * 32, b = blockIdx.y;
  const int hg = blockIdx.z & 1, sp = blockIdx.z >> 1;
  const int h = hg * 4 + w;
  const size_t bh = (size_t)(b * 8 + h);
  const int kvbase = sp * 512;
  const float beta = betap[0];

  // bias staging: thread t covers (q = sqr, kv = skv..skv+7)
  const int sqr = tid >> 3, skv = (tid & 7) * 8;
  const float* ebs = esc + b * 1024;
  const float* wbs = wsc + b * 1024;
  const float eisc = ebs[q0 + sqr];
  const float Kw = 7.2134752f - wbs[q0 + sqr];  // 5*log2e - wsc_i

  auto bias_elem = [&](float ej, float wj) -> float {
    float d = fmaxf(ej - eisc, 0.f);
    float e2 = __builtin_amdgcn_exp2f(Kw - wj);
    float sig = __builtin_amdgcn_rcpf(1.0f + e2);
    float bb = d * beta * sig - d;
    return fminf(fmaxf(bb, -14.4269504f), 0.f);  // clip(-10,0) in log2 units
  };
  auto stage_bias = [&](int kv0) {
    f32x4 ej0 = *reinterpret_cast<const f32x4*>(ebs + kv0 + skv);
    f32x4 ej1 = *reinterpret_cast<const f32x4*>(ebs + kv0 + skv + 4);
    f32x4 wj0 = *reinterpret_cast<const f32x4*>(wbs + kv0 + skv);
    f32x4 wj1 = *reinterpret_cast<const f32x4*>(wbs + kv0 + skv + 4);
    f32x4 o0, o1;
#pragma unroll
    for (int j = 0; j < 4; ++j) {
      o0[j] = bias_elem(ej0[j], wj0[j]);
      o1[j] = bias_elem(ej1[j], wj1[j]);
    }
    *reinterpret_cast<f32x4*>(&bias_lds[sqr][skv]) = o0;
    *reinterpret_cast<f32x4*>(&bias_lds[sqr][skv + 4]) = o1;
  };

  stage_bias(kvbase);

  // Q fragments (B-operand; col = q); q pre-scaled by hd^-0.5*log2e
  short8 qf[2];
#pragma unroll
  for (int qs = 0; qs < 2; ++qs)
    qf[qs] = ld8(qb + (bh * 1024 + q0 + qs * 16 + c) * 32 + g * 8);

  f32x4 oacc[2][2] = {};
  float mold[2] = {-1e30f, -1e30f};
  float lrow[2] = {0.f, 0.f};
  __syncthreads();

  for (int t8 = 0; t8 < 8; ++t8) {
    const int kv0 = kvbase + t8 * 64;

    // K fragments (A-operand; row = kv)
    short8 kf[4];
#pragma unroll
    for (int t = 0; t < 4; ++t)
      kf[t] = ld8(kb + (bh * 1024 + kv0 + t * 16 + c) * 32 + g * 8);

#pragma unroll
    for (int qs = 0; qs < 2; ++qs) {
      // S' = K*Q (log2 domain) + bias' (as MFMA C-operand)
      f32x4 s[4];
#pragma unroll
      for (int t = 0; t < 4; ++t) {
        f32x4 bc = *reinterpret_cast<const f32x4*>(&bias_lds[qs * 16 + c][t * 16 + 4 * g]);
        s[t] = mfma16(kf[t], qf[qs], bc);
      }
      // lane holds S'[q=q0+qs*16+c][kv0 + 16t + 4g + r]
      float m16 = fmaxf(fmaxf(fmaxf(s[0][0], s[0][1]), fmaxf(s[0][2], s[0][3])),
                        fmaxf(fmaxf(s[1][0], s[1][1]), fmaxf(s[1][2], s[1][3])));
      m16 = fmaxf(m16, fmaxf(fmaxf(fmaxf(s[2][0], s[2][1]), fmaxf(s[2][2], s[2][3])),
                             fmaxf(fmaxf(s[3][0], s[3][1]), fmaxf(s[3][2], s[3][3]))));
      m16 = fmaxf(m16, __shfl_xor(m16, 16));
      m16 = fmaxf(m16, __shfl_xor(m16, 32));
      // defer-max: rescale only if max grew by > 11 (log2 units, p <= 2^11)
      if (!__all(m16 <= mold[qs] + 11.0f)) {
        float mn = fmaxf(mold[qs], m16);
        float corr = __builtin_amdgcn_exp2f(mold[qs] - mn);
        mold[qs] = mn;
        lrow[qs] *= corr;
        oacc[qs][0] *= corr;
        oacc[qs][1] *= corr;
      }
      float p[4][4];
      float ps = 0.f;
#pragma unroll
      for (int t = 0; t < 4; ++t)
#pragma unroll
        for (int r = 0; r < 4; ++r) {
          float e = __builtin_amdgcn_exp2f(s[t][r] - mold[qs]);
          p[t][r] = e;
          ps += e;
        }
      ps += __shfl_xor(ps, 16);
      ps += __shfl_xor(ps, 32);
      lrow[qs] += ps;
#pragma unroll
      for (int t = 0; t < 4; ++t) {
        uint2_t pkw = {pk2(p[t][0], p[t][1]), pk2(p[t][2], p[t][3])};
        *reinterpret_cast<uint2_t*>(&p_lds[w][qs * 16 + c][t * 16 + 4 * g]) = pkw;
      }
    }

    __syncthreads();  // all waves done reading bias tile
    if (t8 < 7) stage_bias(kv0 + 64);

    // O^T += V^T * P^T : A = vT rows (d), B = P rows (q), k = kv
#pragma unroll
    for (int t2 = 0; t2 < 2; ++t2) {
      short8 pf[2];
#pragma unroll
      for (int qs = 0; qs < 2; ++qs)
        pf[qs] = ld8(&p_lds[w][qs * 16 + c][t2 * 32 + g * 8]);
#pragma unroll
      for (int hs = 0; hs < 2; ++hs) {
        short8 vf = ld8(vT + (bh * 32 + hs * 16 + c) * 1024 + kv0 + t2 * 32 + g * 8);
#pragma unroll
        for (int qs = 0; qs < 2; ++qs)
          oacc[qs][hs] = mfma16(vf, pf[qs], oacc[qs][hs]);
      }
    }

    __syncthreads();  // bias tile for next iter ready
  }

  // epilogue: unnormalized O^T (lane: O[q=qs*16+c][d=hs*16+4g+r]) + (m,l) in log2 domain
#pragma unroll
  for (int qs = 0; qs < 2; ++qs) {
    size_t qrow = ((size_t)sp * 64 + bh) * 1024 + q0 + qs * 16 + c;
#pragma unroll
    for (int hs = 0; hs < 2; ++hs)
      *reinterpret_cast<f32x4*>(o_part + qrow * 32 + hs * 16 + 4 * g) = oacc[qs][hs];
    if (g == 0) {
      float2_t ml = {mold[qs], lrow[qs]};
      *reinterpret_cast<float2_t*>(ml_part + qrow * 2) = ml;
    }
  }
}

// ---------------- projection fused with kv-split combine ----------------
__global__ __launch_bounds__(256, 2) void k_proj(const float* __restrict__ o_part,
                                                 const float* __restrict__ ml_part,
                                                 const unsigned short* __restrict__ wp_bf,
                                                 const float* __restrict__ bproj,
                                                 float* __restrict__ out) {
  __shared__ unsigned short xs[32][264];
  const int tid = threadIdx.x;
  const int w = tid >> 6, lane = tid & 63;
  const int c = lane & 15, g = lane >> 4;
  const int wm = w & 1, wn = w >> 1;
  const int m0 = blockIdx.x * 32;
  const int b = m0 >> 10, q0 = m0 & 1023;

  // staging: combine sp halves -> bf16 into xs[32][256]
  const int qq = tid >> 3, d0 = (tid & 7) * 4;
#pragma unroll
  for (int h = 0; h < 8; ++h) {
    size_t r0 = ((size_t)(b * 8 + h) * 1024 + q0 + qq);
    size_t r1 = r0 + (size_t)64 * 1024;
    f32x4 o0 = *reinterpret_cast<const f32x4*>(o_part + r0 * 32 + d0);
    f32x4 o1 = *reinterpret_cast<const f32x4*>(o_part + r1 * 32 + d0);
    float2_t ml0 = *reinterpret_cast<const float2_t*>(ml_part + r0 * 2);
    float2_t ml1 = *reinterpret_cast<const float2_t*>(ml_part + r1 * 2);
    float mm = fmaxf(ml0[0], ml1[0]);
    float a0 = __builtin_amdgcn_exp2f(ml0[0] - mm);
    float a1 = __builtin_amdgcn_exp2f(ml1[0] - mm);
    float inv = 1.0f / (a0 * ml0[1] + a1 * ml1[1]);
    f32x4 r;
#pragma unroll
    for (int j = 0; j < 4; ++j) r[j] = (o0[j] * a0 + o1[j] * a1) * inv;
    uint2_t hh = {pk2(r[0], r[1]), pk2(r[2], r[3])};
    *reinterpret_cast<uint2_t*>(&xs[qq][h * 32 + d0]) = hh;
  }
  __syncthreads();

  f32x4 acc[8] = {};
#pragma unroll
  for (int k0 = 0; k0 < 256; k0 += 32) {
    short8 af = ld8(&xs[wm * 16 + c][k0 + g * 8]);
#pragma unroll
    for (int nb = 0; nb < 8; ++nb) {
      short8 bf = ld8(wp_bf + (size_t)(wn * 128 + nb * 16 + c) * 256 + k0 + g * 8);
      acc[nb] = mfma16(af, bf, acc[nb]);
    }
  }
#pragma unroll
  for (int nb = 0; nb < 8; ++nb) {
    int col = wn * 128 + nb * 16 + c;
    float bv = bproj[col];
#pragma unroll
    for (int r = 0; r < 4; ++r) {
      int row = m0 + wm * 16 + g * 4 + r;
      out[(size_t)row * 256 + col] = acc[nb][r] + bv;
    }
  }
}

extern "C" void kernel_launch(void* const* d_in, const int* in_sizes, int n_in,
                              void* d_out, int out_size, void* d_ws, size_t ws_size,
                              hipStream_t stream) {
  const float* x = (const float*)d_in[0];
  const float* elev = (const float*)d_in[1];
  const float* uw = (const float*)d_in[2];
  const float* vw = (const float*)d_in[3];
  const float* wqkv = (const float*)d_in[4];
  const float* wproj = (const float*)d_in[5];
  const float* bproj = (const float*)d_in[6];
  const float* alpha = (const float*)d_in[7];
  const float* beta = (const float*)d_in[8];
  float* out = (float*)d_out;

  char* p = (char*)d_ws;
  auto alloc = [&](size_t bytes) {
    char* r = p;
    p += (bytes + 255) & ~(size_t)255;
    return r;
  };
  float* esc = (float*)alloc(8192 * 4);
  float* wsc = (float*)alloc(8192 * 4);
  unsigned short* wqkv_bf = (unsigned short*)alloc((size_t)768 * 256 * 2);
  unsigned short* wproj_bf = (unsigned short*)alloc((size_t)256 * 256 * 2);
  unsigned short* qb = (unsigned short*)alloc((size_t)2097152 * 2);
  unsigned short* kb = (unsigned short*)alloc((size_t)2097152 * 2);
  unsigned short* vT = (unsigned short*)alloc((size_t)2097152 * 2);
  float* o_part = (float*)alloc((size_t)2 * 2097152 * 4);
  float* ml_part = (float*)alloc((size_t)2 * 65536 * 2 * 4);

  k_prep<<<dim3(1056), dim3(256), 0, stream>>>(wqkv, wproj, uw, vw, elev, alpha,
                                               wqkv_bf, wproj_bf, esc, wsc);
  k_qkv<<<dim3(2, 128), dim3(256), 0, stream>>>(x, wqkv_bf, qb, kb, vT);
  k_attn<<<dim3(32, 8, 4), dim3(256), 0, stream>>>(qb, kb, vT, esc, wsc, beta, o_part, ml_part);
  k_proj<<<dim3(256), dim3(256), 0, stream>>>(o_part, ml_part, wproj_bf, bproj, out);
}

// Round 5
// 152.392 us; speedup vs baseline: 1.0733x; 1.0733x over previous
//
#include <hip/hip_runtime.h>
#include <stdint.h>

typedef __attribute__((ext_vector_type(8))) short short8;
typedef __attribute__((ext_vector_type(8))) __bf16 bf16x8;
typedef __attribute__((ext_vector_type(2))) __bf16 bf16x2;
typedef __attribute__((ext_vector_type(4))) float f32x4;
typedef __attribute__((ext_vector_type(2))) unsigned int uint2_t;
typedef __attribute__((ext_vector_type(2))) float float2_t;

#define LOG2E 1.44269504f

__device__ __forceinline__ unsigned short f2bf(float f) {
  unsigned int u = __builtin_bit_cast(unsigned int, f);
  u += 0x7fffu + ((u >> 16) & 1u);
  return (unsigned short)(u >> 16);
}

// packed f32x2 -> bf16x2 (compiler emits v_cvt_pk_bf16_f32 on gfx950)
__device__ __forceinline__ unsigned int pk2(float a, float b) {
  bf16x2 t;
  t[0] = (__bf16)a;
  t[1] = (__bf16)b;
  return __builtin_bit_cast(unsigned int, t);
}

__device__ __forceinline__ f32x4 mfma16(short8 a, short8 b, f32x4 c) {
  return __builtin_amdgcn_mfma_f32_16x16x32_bf16(
      __builtin_bit_cast(bf16x8, a), __builtin_bit_cast(bf16x8, b), c, 0, 0, 0);
}

__device__ __forceinline__ short8 ld8(const unsigned short* p) {
  return *reinterpret_cast<const short8*>(p);
}

// ---------------- prep: weight cvt (q-scale folded) + scaled wind/elev ----------------
__global__ __launch_bounds__(256) void k_prep(const float* __restrict__ wqkv,
                                              const float* __restrict__ wproj,
                                              const float* __restrict__ u,
                                              const float* __restrict__ v,
                                              const float* __restrict__ elev,
                                              const float* __restrict__ alphap,
                                              unsigned short* __restrict__ wqkv_bf,
                                              unsigned short* __restrict__ wproj_bf,
                                              float* __restrict__ esc,
                                              float* __restrict__ wsc) {
  int gx = blockIdx.x, t = threadIdx.x;
  if (gx < 768) {
    int i = gx * 256 + t;
    // rows [0,256) are q-rows: fold hd^-0.5 * log2e
    float s = (i < 256 * 256) ? (0.17677669529663687f * LOG2E) : 1.0f;
    wqkv_bf[i] = f2bf(wqkv[i] * s);
  } else if (gx < 1024) {
    int i = (gx - 768) * 256 + t;
    wproj_bf[i] = f2bf(wproj[i]);
  } else {
    int i = (gx - 1024) * 256 + t;  // [0, 8192)
    int b = i >> 10, n = i & 1023;
    int ph = n >> 5, pw = n & 31;
    const float* ub = u + b * 4096;
    const float* vb = v + b * 4096;
    float s = 0.f;
#pragma unroll
    for (int dy = 0; dy < 2; ++dy)
#pragma unroll
      for (int dx = 0; dx < 2; ++dx) {
        int idx = (2 * ph + dy) * 64 + (2 * pw + dx);
        float uu = ub[idx], vv = vb[idx];
        s += sqrtf(uu * uu + vv * vv + 1e-8f);
      }
    // wsc = ws * 0.5 * log2e ; esc = elev * alpha * 1e-3 * log2e
    wsc[i] = s * (0.25f * 0.5f * LOG2E);
    esc[i] = elev[i] * (alphap[0] * 1e-3f * LOG2E);
  }
}

// ---------------- QKV GEMM: BM=32, BN=192, 1024 blocks, v written transposed ----
// grid (4, 256); block 256 = 4 waves: wm = w&1 (16-row slice), wn = w>>1 (96-col slice)
__global__ __launch_bounds__(256, 8) void k_qkv(const float* __restrict__ x,
                                                const unsigned short* __restrict__ wq_bf,
                                                unsigned short* __restrict__ qb,
                                                unsigned short* __restrict__ kb,
                                                unsigned short* __restrict__ vT) {
  __shared__ unsigned short xs[32][264];
  const int tid = threadIdx.x;
  const int w = tid >> 6, lane = tid & 63;
  const int c = lane & 15, g = lane >> 4;
  const int wm = w & 1, wn = w >> 1;
  const int m0 = blockIdx.y * 32;
  const int n0 = blockIdx.x * 192 + wn * 96;
  // cooperative coalesced load + convert (32 rows x 256 cols fp32 -> bf16)
#pragma unroll
  for (int i = 0; i < 8; ++i) {
    int idx = i * 1024 + tid * 4;
    int row = idx >> 8, col = idx & 255;
    f32x4 vv = *reinterpret_cast<const f32x4*>(x + (size_t)(m0 + row) * 256 + col);
    uint2_t hh = {pk2(vv[0], vv[1]), pk2(vv[2], vv[3])};
    *reinterpret_cast<uint2_t*>(&xs[row][col]) = hh;
  }
  __syncthreads();
  f32x4 acc[6] = {};
#pragma unroll
  for (int k0 = 0; k0 < 256; k0 += 32) {
    short8 af = ld8(&xs[wm * 16 + c][k0 + g * 8]);
#pragma unroll
    for (int nb = 0; nb < 6; ++nb) {
      short8 bf = ld8(wq_bf + (size_t)(n0 + nb * 16 + c) * 256 + k0 + g * 8);
      acc[nb] = mfma16(af, bf, acc[nb]);
    }
  }
#pragma unroll
  for (int nb = 0; nb < 6; ++nb) {
    int col = n0 + nb * 16 + c;  // [0,768)
    int s = col >> 8, rem = col & 255;
    int h = rem >> 5, d = rem & 31;
    int nrow0 = m0 + wm * 16 + g * 4;  // 4 consecutive rows
    int b = nrow0 >> 10, nn = nrow0 & 1023;
    size_t bh = (size_t)(b * 8 + h);
    if (s == 2) {
      uint2_t pk = {pk2(acc[nb][0], acc[nb][1]), pk2(acc[nb][2], acc[nb][3])};
      *reinterpret_cast<uint2_t*>(vT + (bh * 32 + d) * 1024 + nn) = pk;
    } else {
      unsigned short* dst = (s == 0) ? qb : kb;
#pragma unroll
      for (int r = 0; r < 4; ++r) {
        bf16x2 one;
        one[0] = (__bf16)acc[nb][r];
        dst[(bh * 1024 + nn + r) * 32 + d] = __builtin_bit_cast(unsigned short, one[0]);
      }
    }
  }
}

// ---------------- fused attention: swapped-QK^T, kv-split, f32 bias as MFMA-C ----
// grid: (32 qtiles, 8 b, 4 = hg + 2*sp); block 256 = 4 waves; wave = head hg*4+w
__global__ __launch_bounds__(256, 4) void k_attn(const unsigned short* __restrict__ qb,
                                                 const unsigned short* __restrict__ kb,
                                                 const unsigned short* __restrict__ vT,
                                                 const float* __restrict__ esc,
                                                 const float* __restrict__ wsc,
                                                 const float* __restrict__ betap,
                                                 float* __restrict__ o_part,
                                                 float* __restrict__ ml_part) {
  __shared__ float bias_lds[32][72];
  __shared__ unsigned short p_lds[4][32][72];
  const int tid = threadIdx.x;
  const int w = tid >> 6, lane = tid & 63;
  const int c = lane & 15, g = lane >> 4;
  const int q0 = blockIdx.x * 32, b = blockIdx.y;
  const int hg = blockIdx.z & 1, sp = blockIdx.z >> 1;
  const int h = hg * 4 + w;
  const size_t bh = (size_t)(b * 8 + h);
  const int kvbase = sp * 512;
  const float beta = betap[0];

  // bias staging: thread t covers (q = sqr, kv = skv..skv+7)
  const int sqr = tid >> 3, skv = (tid & 7) * 8;
  const float* ebs = esc + b * 1024;
  const float* wbs = wsc + b * 1024;
  const float eisc = ebs[q0 + sqr];
  const float Kw = 7.2134752f - wbs[q0 + sqr];  // 5*log2e - wsc_i

  auto bias_elem = [&](float ej, float wj) -> float {
    float d = fmaxf(ej - eisc, 0.f);
    float e2 = __builtin_amdgcn_exp2f(Kw - wj);
    float sig = __builtin_amdgcn_rcpf(1.0f + e2);
    float bb = d * beta * sig - d;
    return fminf(fmaxf(bb, -14.4269504f), 0.f);  // clip(-10,0) in log2 units
  };
  auto stage_bias = [&](int kv0) {
    f32x4 ej0 = *reinterpret_cast<const f32x4*>(ebs + kv0 + skv);
    f32x4 ej1 = *reinterpret_cast<const f32x4*>(ebs + kv0 + skv + 4);
    f32x4 wj0 = *reinterpret_cast<const f32x4*>(wbs + kv0 + skv);
    f32x4 wj1 = *reinterpret_cast<const f32x4*>(wbs + kv0 + skv + 4);
    f32x4 o0, o1;
#pragma unroll
    for (int j = 0; j < 4; ++j) {
      o0[j] = bias_elem(ej0[j], wj0[j]);
      o1[j] = bias_elem(ej1[j], wj1[j]);
    }
    *reinterpret_cast<f32x4*>(&bias_lds[sqr][skv]) = o0;
    *reinterpret_cast<f32x4*>(&bias_lds[sqr][skv + 4]) = o1;
  };

  stage_bias(kvbase);

  // Q fragments (B-operand; col = q); q pre-scaled by hd^-0.5*log2e
  short8 qf[2];
#pragma unroll
  for (int qs = 0; qs < 2; ++qs)
    qf[qs] = ld8(qb + (bh * 1024 + q0 + qs * 16 + c) * 32 + g * 8);

  f32x4 oacc[2][2] = {};
  float mold[2] = {-1e30f, -1e30f};
  float lrow[2] = {0.f, 0.f};
  __syncthreads();

  for (int t8 = 0; t8 < 8; ++t8) {
    const int kv0 = kvbase + t8 * 64;

    // K fragments (A-operand; row = kv)
    short8 kf[4];
#pragma unroll
    for (int t = 0; t < 4; ++t)
      kf[t] = ld8(kb + (bh * 1024 + kv0 + t * 16 + c) * 32 + g * 8);

#pragma unroll
    for (int qs = 0; qs < 2; ++qs) {
      // S' = K*Q (log2 domain) + bias' (as MFMA C-operand)
      f32x4 s[4];
#pragma unroll
      for (int t = 0; t < 4; ++t) {
        f32x4 bc = *reinterpret_cast<const f32x4*>(&bias_lds[qs * 16 + c][t * 16 + 4 * g]);
        s[t] = mfma16(kf[t], qf[qs], bc);
      }
      // lane holds S'[q=q0+qs*16+c][kv0 + 16t + 4g + r]
      float m16 = fmaxf(fmaxf(fmaxf(s[0][0], s[0][1]), fmaxf(s[0][2], s[0][3])),
                        fmaxf(fmaxf(s[1][0], s[1][1]), fmaxf(s[1][2], s[1][3])));
      m16 = fmaxf(m16, fmaxf(fmaxf(fmaxf(s[2][0], s[2][1]), fmaxf(s[2][2], s[2][3])),
                             fmaxf(fmaxf(s[3][0], s[3][1]), fmaxf(s[3][2], s[3][3]))));
      m16 = fmaxf(m16, __shfl_xor(m16, 16));
      m16 = fmaxf(m16, __shfl_xor(m16, 32));
      // defer-max: rescale only if max grew by > 11 (log2 units, p <= 2^11)
      if (!__all(m16 <= mold[qs] + 11.0f)) {
        float mn = fmaxf(mold[qs], m16);
        float corr = __builtin_amdgcn_exp2f(mold[qs] - mn);
        mold[qs] = mn;
        lrow[qs] *= corr;
        oacc[qs][0] *= corr;
        oacc[qs][1] *= corr;
      }
      float p[4][4];
      float ps = 0.f;
#pragma unroll
      for (int t = 0; t < 4; ++t)
#pragma unroll
        for (int r = 0; r < 4; ++r) {
          float e = __builtin_amdgcn_exp2f(s[t][r] - mold[qs]);
          p[t][r] = e;
          ps += e;
        }
      ps += __shfl_xor(ps, 16);
      ps += __shfl_xor(ps, 32);
      lrow[qs] += ps;
#pragma unroll
      for (int t = 0; t < 4; ++t) {
        uint2_t pkw = {pk2(p[t][0], p[t][1]), pk2(p[t][2], p[t][3])};
        *reinterpret_cast<uint2_t*>(&p_lds[w][qs * 16 + c][t * 16 + 4 * g]) = pkw;
      }
    }

    __syncthreads();  // all waves done reading bias tile
    if (t8 < 7) stage_bias(kv0 + 64);

    // O^T += V^T * P^T : A = vT rows (d), B = P rows (q), k = kv
#pragma unroll
    for (int t2 = 0; t2 < 2; ++t2) {
      short8 pf[2];
#pragma unroll
      for (int qs = 0; qs < 2; ++qs)
        pf[qs] = ld8(&p_lds[w][qs * 16 + c][t2 * 32 + g * 8]);
#pragma unroll
      for (int hs = 0; hs < 2; ++hs) {
        short8 vf = ld8(vT + (bh * 32 + hs * 16 + c) * 1024 + kv0 + t2 * 32 + g * 8);
#pragma unroll
        for (int qs = 0; qs < 2; ++qs)
          oacc[qs][hs] = mfma16(vf, pf[qs], oacc[qs][hs]);
      }
    }

    __syncthreads();  // bias tile for next iter ready
  }

  // epilogue: unnormalized O^T (lane: O[q=qs*16+c][d=hs*16+4g+r]) + (m,l) in log2 domain
#pragma unroll
  for (int qs = 0; qs < 2; ++qs) {
    size_t qrow = ((size_t)sp * 64 + bh) * 1024 + q0 + qs * 16 + c;
#pragma unroll
    for (int hs = 0; hs < 2; ++hs)
      *reinterpret_cast<f32x4*>(o_part + qrow * 32 + hs * 16 + 4 * g) = oacc[qs][hs];
    if (g == 0) {
      float2_t ml = {mold[qs], lrow[qs]};
      *reinterpret_cast<float2_t*>(ml_part + qrow * 2) = ml;
    }
  }
}

// ---------------- projection fused with kv-split combine ----------------
__global__ __launch_bounds__(256, 2) void k_proj(const float* __restrict__ o_part,
                                                 const float* __restrict__ ml_part,
                                                 const unsigned short* __restrict__ wp_bf,
                                                 const float* __restrict__ bproj,
                                                 float* __restrict__ out) {
  __shared__ unsigned short xs[32][264];
  const int tid = threadIdx.x;
  const int w = tid >> 6, lane = tid & 63;
  const int c = lane & 15, g = lane >> 4;
  const int wm = w & 1, wn = w >> 1;
  const int m0 = blockIdx.x * 32;
  const int b = m0 >> 10, q0 = m0 & 1023;

  // staging: combine sp halves -> bf16 into xs[32][256]
  const int qq = tid >> 3, d0 = (tid & 7) * 4;
#pragma unroll
  for (int h = 0; h < 8; ++h) {
    size_t r0 = ((size_t)(b * 8 + h) * 1024 + q0 + qq);
    size_t r1 = r0 + (size_t)64 * 1024;
    f32x4 o0 = *reinterpret_cast<const f32x4*>(o_part + r0 * 32 + d0);
    f32x4 o1 = *reinterpret_cast<const f32x4*>(o_part + r1 * 32 + d0);
    float2_t ml0 = *reinterpret_cast<const float2_t*>(ml_part + r0 * 2);
    float2_t ml1 = *reinterpret_cast<const float2_t*>(ml_part + r1 * 2);
    float mm = fmaxf(ml0[0], ml1[0]);
    float a0 = __builtin_amdgcn_exp2f(ml0[0] - mm);
    float a1 = __builtin_amdgcn_exp2f(ml1[0] - mm);
    float inv = 1.0f / (a0 * ml0[1] + a1 * ml1[1]);
    f32x4 r;
#pragma unroll
    for (int j = 0; j < 4; ++j) r[j] = (o0[j] * a0 + o1[j] * a1) * inv;
    uint2_t hh = {pk2(r[0], r[1]), pk2(r[2], r[3])};
    *reinterpret_cast<uint2_t*>(&xs[qq][h * 32 + d0]) = hh;
  }
  __syncthreads();

  f32x4 acc[8] = {};
#pragma unroll
  for (int k0 = 0; k0 < 256; k0 += 32) {
    short8 af = ld8(&xs[wm * 16 + c][k0 + g * 8]);
#pragma unroll
    for (int nb = 0; nb < 8; ++nb) {
      short8 bf = ld8(wp_bf + (size_t)(wn * 128 + nb * 16 + c) * 256 + k0 + g * 8);
      acc[nb] = mfma16(af, bf, acc[nb]);
    }
  }
#pragma unroll
  for (int nb = 0; nb < 8; ++nb) {
    int col = wn * 128 + nb * 16 + c;
    float bv = bproj[col];
#pragma unroll
    for (int r = 0; r < 4; ++r) {
      int row = m0 + wm * 16 + g * 4 + r;
      out[(size_t)row * 256 + col] = acc[nb][r] + bv;
    }
  }
}

extern "C" void kernel_launch(void* const* d_in, const int* in_sizes, int n_in,
                              void* d_out, int out_size, void* d_ws, size_t ws_size,
                              hipStream_t stream) {
  const float* x = (const float*)d_in[0];
  const float* elev = (const float*)d_in[1];
  const float* uw = (const float*)d_in[2];
  const float* vw = (const float*)d_in[3];
  const float* wqkv = (const float*)d_in[4];
  const float* wproj = (const float*)d_in[5];
  const float* bproj = (const float*)d_in[6];
  const float* alpha = (const float*)d_in[7];
  const float* beta = (const float*)d_in[8];
  float* out = (float*)d_out;

  char* p = (char*)d_ws;
  auto alloc = [&](size_t bytes) {
    char* r = p;
    p += (bytes + 255) & ~(size_t)255;
    return r;
  };
  float* esc = (float*)alloc(8192 * 4);
  float* wsc = (float*)alloc(8192 * 4);
  unsigned short* wqkv_bf = (unsigned short*)alloc((size_t)768 * 256 * 2);
  unsigned short* wproj_bf = (unsigned short*)alloc((size_t)256 * 256 * 2);
  unsigned short* qb = (unsigned short*)alloc((size_t)2097152 * 2);
  unsigned short* kb = (unsigned short*)alloc((size_t)2097152 * 2);
  unsigned short* vT = (unsigned short*)alloc((size_t)2097152 * 2);
  float* o_part = (float*)alloc((size_t)2 * 2097152 * 4);
  float* ml_part = (float*)alloc((size_t)2 * 65536 * 2 * 4);

  k_prep<<<dim3(1056), dim3(256), 0, stream>>>(wqkv, wproj, uw, vw, elev, alpha,
                                               wqkv_bf, wproj_bf, esc, wsc);
  k_qkv<<<dim3(4, 256), dim3(256), 0, stream>>>(x, wqkv_bf, qb, kb, vT);
  k_attn<<<dim3(32, 8, 4), dim3(256), 0, stream>>>(qb, kb, vT, esc, wsc, beta, o_part, ml_part);
  k_proj<<<dim3(256), dim3(256), 0, stream>>>(o_part, ml_part, wproj_bf, bproj, out);
}